// Round 8
// baseline (1379.127 us; speedup 1.0000x reference)
//
#include <hip/hip_runtime.h>
#include <hip/hip_bf16.h>

#define NN 100000
#define EE 1000000
#define GG 128
#define NT 782               // node tiles of 128 (782*128 = 100096)
#define BN_EPS 1e-5f

// workspace float offsets
#define X_OFF     0L          // x as packed bf16 [100096][64] ushorts (3,203,072 floats)
#define T_OFF     6400000L    // tiled f32 [NT][64][128]
#define WT1_OFF   12806144L   // fh layer1 scaled cols [128][64]
#define C1_OFF    12814336L
#define WT2_OFF   12814400L   // fh layer2 scaled cols [64][64]
#define C2_OFF    12818496L
#define WTC1_OFF  12818560L   // conv layer1 x3
#define CC1_OFF   12830848L
#define WTC2_OFF  12831040L   // conv layer2 x3
#define CC2_OFF   12843328L
#define POOL_OFF  12843520L   // 4 stages * 128 * 64
#define CNT_OFF   12876288L   // 128
// int-typed views
#define COL_OFF   12876416L   // 1,000,000
#define CUR_OFF   13876416L   // 100,000
#define BSUM_OFF  13976416L   // 128

#define SCAN_BLK 1024
#define SCAN_NBLK ((NN + SCAN_BLK - 1) / SCAN_BLK)   // 98

__device__ __forceinline__ float bf_lo(unsigned v) { return __uint_as_float(v << 16); }
__device__ __forceinline__ float bf_hi(unsigned v) { return __uint_as_float(v & 0xffff0000u); }
__device__ __forceinline__ unsigned f2bf(float f) {
    unsigned b = __float_as_uint(f);
    return (b + 0x7fffu + ((b >> 16) & 1u)) >> 16;   // RNE
}

// ---------------- prep: fold BN scale into weight columns ----------------
__global__ void prep_kernel(
    const float* __restrict__ fh_W1, const float* __restrict__ fh_b1, const float* __restrict__ fh_g1,
    const float* __restrict__ fh_bt1, const float* __restrict__ fh_m1, const float* __restrict__ fh_v1,
    const float* __restrict__ fh_W2, const float* __restrict__ fh_b2, const float* __restrict__ fh_g2,
    const float* __restrict__ fh_bt2, const float* __restrict__ fh_m2, const float* __restrict__ fh_v2,
    const float* __restrict__ cW1, const float* __restrict__ cb1, const float* __restrict__ cg1,
    const float* __restrict__ cbt1, const float* __restrict__ cm1, const float* __restrict__ cv1,
    const float* __restrict__ cW2, const float* __restrict__ cb2, const float* __restrict__ cg2,
    const float* __restrict__ cbt2, const float* __restrict__ cm2, const float* __restrict__ cv2,
    float* __restrict__ ws)
{
    int job = blockIdx.x;
    const float *W, *b, *g, *bt, *m, *v;
    float *Wo, *Co;
    int K;
    if (job == 0) {
        W = fh_W1; b = fh_b1; g = fh_g1; bt = fh_bt1; m = fh_m1; v = fh_v1;
        Wo = ws + WT1_OFF; Co = ws + C1_OFF; K = 128;
    } else if (job == 1) {
        W = fh_W2; b = fh_b2; g = fh_g2; bt = fh_bt2; m = fh_m2; v = fh_v2;
        Wo = ws + WT2_OFF; Co = ws + C2_OFF; K = 64;
    } else if (job <= 4) {
        int l = job - 2;
        W = cW1 + l * 4096; b = cb1 + l * 64; g = cg1 + l * 64; bt = cbt1 + l * 64;
        m = cm1 + l * 64; v = cv1 + l * 64;
        Wo = ws + WTC1_OFF + l * 4096; Co = ws + CC1_OFF + l * 64; K = 64;
    } else {
        int l = job - 5;
        W = cW2 + l * 4096; b = cb2 + l * 64; g = cg2 + l * 64; bt = cbt2 + l * 64;
        m = cm2 + l * 64; v = cv2 + l * 64;
        Wo = ws + WTC2_OFF + l * 4096; Co = ws + CC2_OFF + l * 64; K = 64;
    }
    int tot = 64 * K;
    for (int i = threadIdx.x; i < tot; i += blockDim.x) {
        int j = i & 63;
        float s = g[j] * rsqrtf(v[j] + BN_EPS);
        Wo[i] = W[i] * s;   // [k][j] layout, scale column j
    }
    if (threadIdx.x < 64) {
        int j = threadIdx.x;
        float s = g[j] * rsqrtf(v[j] + BN_EPS);
        Co[j] = (b[j] - m[j]) * s + bt[j];
    }
}

// ---------------- CSR build ----------------
__global__ __launch_bounds__(256) void hist_kernel(const int* __restrict__ edges, int* __restrict__ cnt)
{
    int e = blockIdx.x * blockDim.x + threadIdx.x;
    if (e >= EE) return;
    atomicAdd(&cnt[edges[EE + e]], 1);
}

__global__ __launch_bounds__(SCAN_BLK) void scan_pass1(const int* __restrict__ cnt, int* __restrict__ bsum)
{
    __shared__ int r[SCAN_BLK];
    int t = threadIdx.x;
    int i = blockIdx.x * SCAN_BLK + t;
    r[t] = (i < NN) ? cnt[i] : 0;
    __syncthreads();
    for (int off = SCAN_BLK / 2; off > 0; off >>= 1) {
        if (t < off) r[t] += r[t + off];
        __syncthreads();
    }
    if (t == 0) bsum[blockIdx.x] = r[0];
}

__global__ __launch_bounds__(128) void scan_pass2(int* __restrict__ bsum)
{
    __shared__ int s[128];
    int t = threadIdx.x;
    int v = (t < SCAN_NBLK) ? bsum[t] : 0;
    s[t] = v;
    __syncthreads();
    for (int off = 1; off < 128; off <<= 1) {
        int a = (t >= off) ? s[t - off] : 0;
        __syncthreads();
        s[t] += a;
        __syncthreads();
    }
    if (t < SCAN_NBLK) bsum[t] = s[t] - v;   // exclusive
}

__global__ __launch_bounds__(SCAN_BLK) void scan_pass3(int* __restrict__ cnt, const int* __restrict__ bsum)
{
    __shared__ int s[SCAN_BLK];
    int t = threadIdx.x;
    int i = blockIdx.x * SCAN_BLK + t;
    int v = (i < NN) ? cnt[i] : 0;
    s[t] = v;
    __syncthreads();
    for (int off = 1; off < SCAN_BLK; off <<= 1) {
        int a = (t >= off) ? s[t - off] : 0;
        __syncthreads();
        s[t] += a;
        __syncthreads();
    }
    if (i < NN) cnt[i] = bsum[blockIdx.x] + s[t] - v;   // exclusive start
}

__global__ __launch_bounds__(256) void fill_kernel(
    const int* __restrict__ edges, int* __restrict__ cursor, int* __restrict__ col)
{
    int e = blockIdx.x * blockDim.x + threadIdx.x;
    if (e >= EE) return;
    int dst = edges[EE + e];
    int p = atomicAdd(&cursor[dst], 1);
    col[p] = edges[e];
}
// after fill: cursor[n] == row end; start = (n==0)?0:cursor[n-1]

// ---------------- gather: agg = x + sum x[src] from bf16 x; writes tiled f32 T ----------------
__global__ __launch_bounds__(256) void gather_t_kernel(
    const unsigned* __restrict__ xb, const int* __restrict__ cursor, const int* __restrict__ col,
    float* __restrict__ T)
{
    __shared__ float lds[64 * 65];
    int half = blockIdx.x & 1;
    int tile = blockIdx.x >> 1;
    int nbase = blockIdx.x << 6;
    int wv = threadIdx.x >> 6, lane = threadIdx.x & 63;
    int q = lane >> 3, c = lane & 7;   // 8 neighbor slots x 8 uint4-columns
    const uint4* x4 = (const uint4*)xb;
    for (int s = 0; s < 16; s++) {
        int i = wv * 16 + s;            // 0..63 within block
        int n = nbase + i;
        if (n < NN) {
            int st = (n == 0) ? 0 : cursor[n - 1];
            int en = cursor[n];
            float acc[8];
            if (q == 0) {
                uint4 u = x4[(long)n * 8 + c];
                acc[0] = bf_lo(u.x); acc[1] = bf_hi(u.x);
                acc[2] = bf_lo(u.y); acc[3] = bf_hi(u.y);
                acc[4] = bf_lo(u.z); acc[5] = bf_hi(u.z);
                acc[6] = bf_lo(u.w); acc[7] = bf_hi(u.w);
            } else {
#pragma unroll
                for (int r = 0; r < 8; r++) acc[r] = 0.f;
            }
            for (int b = st + q; b < en; b += 8) {
                int sc = col[b];
                uint4 u = x4[(long)sc * 8 + c];
                acc[0] += bf_lo(u.x); acc[1] += bf_hi(u.x);
                acc[2] += bf_lo(u.y); acc[3] += bf_hi(u.y);
                acc[4] += bf_lo(u.z); acc[5] += bf_hi(u.z);
                acc[6] += bf_lo(u.w); acc[7] += bf_hi(u.w);
            }
#pragma unroll
            for (int d = 8; d <= 32; d <<= 1) {
#pragma unroll
                for (int r = 0; r < 8; r++) acc[r] += __shfl_xor(acc[r], d);
            }
            if (q == 0) {
                int f = c << 3;
#pragma unroll
                for (int r = 0; r < 8; r++) lds[(f + r) * 65 + i] = acc[r];
            }
        }
    }
    __syncthreads();
    long gb = (long)tile * 8192 + (half << 6);
    for (int idx = threadIdx.x; idx < 4096; idx += 256) {
        int j = idx >> 6, i2 = idx & 63;
        T[gb + j * 128 + i2] = lds[j * 65 + i2];
    }
}

// ---------------- fused conv MLP: T (f32 tiled) -> x (bf16), 64 nodes x 4 segs ----------------
__global__ __launch_bounds__(256) void conv_fused_kernel(
    const float* __restrict__ T,
    const float* __restrict__ W1s, const float* __restrict__ C1v,
    const float* __restrict__ W2s, const float* __restrict__ C2v,
    unsigned* __restrict__ xb)
{
    __shared__ float h[64 * 65];
    int t = threadIdx.x;
    int seg = t & 3, il = t >> 2;          // node-local 0..63
    int half = blockIdx.x & 1, tile = blockIdx.x >> 1;
    int n = (blockIdx.x << 6) + il;
    const float* base = T + (long)tile * 8192 + (half << 6) + il;
    float a[16];
#pragma unroll
    for (int j = 0; j < 16; j++) a[j] = C1v[seg * 16 + j];
    for (int k = 0; k < 64; k += 4) {
        float x0 = base[(k + 0) * 128];
        float x1 = base[(k + 1) * 128];
        float x2 = base[(k + 2) * 128];
        float x3 = base[(k + 3) * 128];
        const float* w = W1s + k * 64 + seg * 16;
#pragma unroll
        for (int j = 0; j < 16; j++) a[j] += x0 * w[j];
#pragma unroll
        for (int j = 0; j < 16; j++) a[j] += x1 * w[64 + j];
#pragma unroll
        for (int j = 0; j < 16; j++) a[j] += x2 * w[128 + j];
#pragma unroll
        for (int j = 0; j < 16; j++) a[j] += x3 * w[192 + j];
    }
    float* hrow = h + il * 65;
#pragma unroll
    for (int j = 0; j < 16; j++) hrow[seg * 16 + j] = fmaxf(a[j], 0.f);
    __syncthreads();
    float o[16];
#pragma unroll
    for (int j = 0; j < 16; j++) o[j] = C2v[seg * 16 + j];
    for (int k = 0; k < 64; k += 4) {
        float x0 = hrow[k], x1 = hrow[k + 1], x2 = hrow[k + 2], x3 = hrow[k + 3];
        const float* w = W2s + k * 64 + seg * 16;
#pragma unroll
        for (int j = 0; j < 16; j++) o[j] += x0 * w[j];
#pragma unroll
        for (int j = 0; j < 16; j++) o[j] += x1 * w[64 + j];
#pragma unroll
        for (int j = 0; j < 16; j++) o[j] += x2 * w[128 + j];
#pragma unroll
        for (int j = 0; j < 16; j++) o[j] += x3 * w[192 + j];
    }
    if (n < NN) {
        unsigned u[8];
#pragma unroll
        for (int p = 0; p < 8; p++) {
            float lo = fmaxf(o[2 * p], 0.f), hi = fmaxf(o[2 * p + 1], 0.f);
            u[p] = f2bf(lo) | (f2bf(hi) << 16);
        }
        uint4* xo = (uint4*)(xb + (long)n * 32 + seg * 8);
        xo[0] = make_uint4(u[0], u[1], u[2], u[3]);
        xo[1] = make_uint4(u[4], u[5], u[6], u[7]);
    }
}

// ---------------- fused first MLP: embedding gather -> x (bf16), 64 nodes x 4 segs ----------------
__global__ __launch_bounds__(256) void embed_fused_kernel(
    const int* __restrict__ node_ids, const float* __restrict__ emb,
    const float* __restrict__ W1s, const float* __restrict__ C1v,
    const float* __restrict__ W2s, const float* __restrict__ C2v,
    unsigned* __restrict__ xb)
{
    __shared__ float h[64 * 65];
    int t = threadIdx.x;
    int seg = t & 3, il = t >> 2;
    int n = (blockIdx.x << 6) + il;
    float a[16];
#pragma unroll
    for (int j = 0; j < 16; j++) a[j] = C1v[seg * 16 + j];
    if (n < NN) {
        long nid = node_ids[n];
        const float4* e4 = (const float4*)(emb + nid * 128);
#pragma unroll 4
        for (int q = 0; q < 32; q++) {
            float4 tq = e4[q];
            const float* w = W1s + q * 256 + seg * 16;
#pragma unroll
            for (int j = 0; j < 16; j++) a[j] += tq.x * w[j];
#pragma unroll
            for (int j = 0; j < 16; j++) a[j] += tq.y * w[64 + j];
#pragma unroll
            for (int j = 0; j < 16; j++) a[j] += tq.z * w[128 + j];
#pragma unroll
            for (int j = 0; j < 16; j++) a[j] += tq.w * w[192 + j];
        }
    }
    float* hrow = h + il * 65;
#pragma unroll
    for (int j = 0; j < 16; j++) hrow[seg * 16 + j] = fmaxf(a[j], 0.f);
    __syncthreads();
    float o[16];
#pragma unroll
    for (int j = 0; j < 16; j++) o[j] = C2v[seg * 16 + j];
    for (int k = 0; k < 64; k += 4) {
        float x0 = hrow[k], x1 = hrow[k + 1], x2 = hrow[k + 2], x3 = hrow[k + 3];
        const float* w = W2s + k * 64 + seg * 16;
#pragma unroll
        for (int j = 0; j < 16; j++) o[j] += x0 * w[j];
#pragma unroll
        for (int j = 0; j < 16; j++) o[j] += x1 * w[64 + j];
#pragma unroll
        for (int j = 0; j < 16; j++) o[j] += x2 * w[128 + j];
#pragma unroll
        for (int j = 0; j < 16; j++) o[j] += x3 * w[192 + j];
    }
    if (n < NN) {
        unsigned u[8];
#pragma unroll
        for (int p = 0; p < 8; p++) {
            float lo = fmaxf(o[2 * p], 0.f), hi = fmaxf(o[2 * p + 1], 0.f);
            u[p] = f2bf(lo) | (f2bf(hi) << 16);
        }
        uint4* xo = (uint4*)(xb + (long)n * 32 + seg * 8);
        xo[0] = make_uint4(u[0], u[1], u[2], u[3]);
        xo[1] = make_uint4(u[4], u[5], u[6], u[7]);
    }
}

// ---------------- graph pooling over sorted batch from bf16 x ----------------
#define POOL_WAVES 4096
#define POOL_CHUNK ((NN + POOL_WAVES - 1) / POOL_WAVES)   // 25
__global__ __launch_bounds__(256) void pool_kernel(
    const unsigned short* __restrict__ xb, const int* __restrict__ batch,
    float* __restrict__ pooled, float* __restrict__ cnt)
{
    int wave = (blockIdx.x * blockDim.x + threadIdx.x) >> 6;
    int lane = threadIdx.x & 63;
    int start = wave * POOL_CHUNK;
    int end = start + POOL_CHUNK;
    if (end > NN) end = NN;
    if (start >= end) return;
    int g_cur = batch[start];
    float acc = 0.f, c = 0.f;
    for (int n = start; n < end; ++n) {
        int g = batch[n];
        if (g != g_cur) {
            unsafeAtomicAdd(&pooled[(long)g_cur * 64 + lane], acc);
            if (cnt != nullptr && lane == 0) unsafeAtomicAdd(&cnt[g_cur], c);
            acc = 0.f; c = 0.f; g_cur = g;
        }
        acc += __uint_as_float(((unsigned)xb[(long)n * 64 + lane]) << 16);
        c += 1.f;
    }
    unsafeAtomicAdd(&pooled[(long)g_cur * 64 + lane], acc);
    if (cnt != nullptr && lane == 0) unsafeAtomicAdd(&cnt[g_cur], c);
}

// ---------------- readout + softmax ----------------
__global__ void final_kernel(
    const float* __restrict__ pooled, const float* __restrict__ cnt,
    const float* __restrict__ linW, const float* __restrict__ linb,
    float* __restrict__ outp)
{
    int g = threadIdx.x;
    if (g >= GG) return;
    float z0 = 0.f, z1 = 0.f;
    float c = cnt[g];
    for (int l = 0; l < 4; l++) {
        const float* p = pooled + (long)l * GG * 64 + (long)g * 64;
        const float* W = linW + l * 128;
        float bscale = (l == 0) ? c : 1.f;   // layer0 bias summed per node; others once
        float s0 = linb[l * 2 + 0] * bscale;
        float s1 = linb[l * 2 + 1] * bscale;
        for (int k = 0; k < 64; k++) {
            float pk = p[k];
            s0 += pk * W[k * 2 + 0];
            s1 += pk * W[k * 2 + 1];
        }
        z0 += s0; z1 += s1;
    }
    float mx = fmaxf(z0, z1);
    float e0 = expf(z0 - mx), e1 = expf(z1 - mx);
    float inv = 1.f / (e0 + e1);
    outp[g * 2 + 0] = e0 * inv;
    outp[g * 2 + 1] = e1 * inv;
}

extern "C" void kernel_launch(void* const* d_in, const int* in_sizes, int n_in,
                              void* d_out, int out_size, void* d_ws, size_t ws_size,
                              hipStream_t stream) {
    const int*   node_ids = (const int*)d_in[0];
    const int*   edges    = (const int*)d_in[1];
    const int*   batch    = (const int*)d_in[2];
    const float* emb      = (const float*)d_in[3];
    const float* fh_W1 = (const float*)d_in[4];
    const float* fh_b1 = (const float*)d_in[5];
    const float* fh_g1 = (const float*)d_in[6];
    const float* fh_bt1 = (const float*)d_in[7];
    const float* fh_m1 = (const float*)d_in[8];
    const float* fh_v1 = (const float*)d_in[9];
    const float* fh_W2 = (const float*)d_in[10];
    const float* fh_b2 = (const float*)d_in[11];
    const float* fh_g2 = (const float*)d_in[12];
    const float* fh_bt2 = (const float*)d_in[13];
    const float* fh_m2 = (const float*)d_in[14];
    const float* fh_v2 = (const float*)d_in[15];
    const float* cW1 = (const float*)d_in[16];
    const float* cb1 = (const float*)d_in[17];
    const float* cg1 = (const float*)d_in[18];
    const float* cbt1 = (const float*)d_in[19];
    const float* cm1 = (const float*)d_in[20];
    const float* cv1 = (const float*)d_in[21];
    const float* cW2 = (const float*)d_in[22];
    const float* cb2 = (const float*)d_in[23];
    const float* cg2 = (const float*)d_in[24];
    const float* cbt2 = (const float*)d_in[25];
    const float* cm2 = (const float*)d_in[26];
    const float* cv2 = (const float*)d_in[27];
    const float* linW = (const float*)d_in[28];
    const float* linb = (const float*)d_in[29];

    float*    ws     = (float*)d_ws;
    int*      cursor = (int*)(ws + CUR_OFF);
    int*      col    = (int*)(ws + COL_OFF);
    int*      bsum   = (int*)(ws + BSUM_OFF);
    float*    Tt     = ws + T_OFF;
    unsigned* xb     = (unsigned*)(ws + X_OFF);

    prep_kernel<<<8, 256, 0, stream>>>(
        fh_W1, fh_b1, fh_g1, fh_bt1, fh_m1, fh_v1,
        fh_W2, fh_b2, fh_g2, fh_bt2, fh_m2, fh_v2,
        cW1, cb1, cg1, cbt1, cm1, cv1,
        cW2, cb2, cg2, cbt2, cm2, cv2, ws);

    hipMemsetAsync(ws + POOL_OFF, 0, (4L * GG * 64 + GG) * sizeof(float), stream);
    hipMemsetAsync(cursor, 0, NN * sizeof(int), stream);

    // CSR build (dst-indexed, single-pass fill)
    hist_kernel<<<(EE + 255) / 256, 256, 0, stream>>>(edges, cursor);
    scan_pass1<<<SCAN_NBLK, SCAN_BLK, 0, stream>>>(cursor, bsum);
    scan_pass2<<<1, 128, 0, stream>>>(bsum);
    scan_pass3<<<SCAN_NBLK, SCAN_BLK, 0, stream>>>(cursor, bsum);
    fill_kernel<<<(EE + 255) / 256, 256, 0, stream>>>(edges, cursor, col);

    const int FBLK = NT * 2;   // 1564 blocks (64 nodes each)

    embed_fused_kernel<<<FBLK, 256, 0, stream>>>(
        node_ids, emb, ws + WT1_OFF, ws + C1_OFF, ws + WT2_OFF, ws + C2_OFF, xb);

    pool_kernel<<<POOL_WAVES / 4, 256, 0, stream>>>(
        (const unsigned short*)xb, batch, ws + POOL_OFF, ws + CNT_OFF);

    for (int l = 0; l < 3; l++) {
        gather_t_kernel<<<FBLK, 256, 0, stream>>>(xb, cursor, col, Tt);
        conv_fused_kernel<<<FBLK, 256, 0, stream>>>(
            Tt, ws + WTC1_OFF + l * 4096, ws + CC1_OFF + l * 64,
            ws + WTC2_OFF + l * 4096, ws + CC2_OFF + l * 64, xb);
        pool_kernel<<<POOL_WAVES / 4, 256, 0, stream>>>(
            (const unsigned short*)xb, batch, ws + POOL_OFF + (long)(l + 1) * GG * 64, nullptr);
    }

    final_kernel<<<1, 128, 0, stream>>>(
        ws + POOL_OFF, ws + CNT_OFF, linW, linb, (float*)d_out);
}

// Round 9
// 611.336 us; speedup vs baseline: 2.2559x; 2.2559x over previous
//
#include <hip/hip_runtime.h>
#include <hip/hip_bf16.h>

#define NN 100000
#define EE 1000000
#define GG 128
#define NT 782               // node tiles of 128 (782*128 = 100096)
#define BN_EPS 1e-5f

// workspace float offsets
#define X_OFF     0L          // x as packed bf16 [100096][64] ushorts
#define T_OFF     6400000L    // tiled f32 [NT][64][128]
#define WT1_OFF   12806144L   // fh layer1 scaled cols [128][64]
#define C1_OFF    12814336L
#define WT2_OFF   12814400L   // fh layer2 scaled cols [64][64]
#define C2_OFF    12818496L
#define WTC1_OFF  12818560L   // conv layer1 x3
#define CC1_OFF   12830848L
#define WTC2_OFF  12831040L   // conv layer2 x3
#define CC2_OFF   12843328L
#define POOL_OFF  12843520L   // 4 stages * 128 * 64
#define CNT_OFF   12876288L   // 128
// int-typed views
#define COL_OFF   12876416L   // 1,000,000
#define CUR_OFF   13876416L   // 100,000
#define BSUM_OFF  13976416L   // 128

#define SCAN_BLK 1024
#define SCAN_NBLK ((NN + SCAN_BLK - 1) / SCAN_BLK)   // 98

__device__ __forceinline__ float bf_lo(unsigned v) { return __uint_as_float(v << 16); }
__device__ __forceinline__ float bf_hi(unsigned v) { return __uint_as_float(v & 0xffff0000u); }
__device__ __forceinline__ unsigned f2bf(float f) {
    unsigned b = __float_as_uint(f);
    return (b + 0x7fffu + ((b >> 16) & 1u)) >> 16;   // RNE
}

// ---------------- prep: fold BN scale into weight columns ----------------
__global__ void prep_kernel(
    const float* __restrict__ fh_W1, const float* __restrict__ fh_b1, const float* __restrict__ fh_g1,
    const float* __restrict__ fh_bt1, const float* __restrict__ fh_m1, const float* __restrict__ fh_v1,
    const float* __restrict__ fh_W2, const float* __restrict__ fh_b2, const float* __restrict__ fh_g2,
    const float* __restrict__ fh_bt2, const float* __restrict__ fh_m2, const float* __restrict__ fh_v2,
    const float* __restrict__ cW1, const float* __restrict__ cb1, const float* __restrict__ cg1,
    const float* __restrict__ cbt1, const float* __restrict__ cm1, const float* __restrict__ cv1,
    const float* __restrict__ cW2, const float* __restrict__ cb2, const float* __restrict__ cg2,
    const float* __restrict__ cbt2, const float* __restrict__ cm2, const float* __restrict__ cv2,
    float* __restrict__ ws)
{
    int job = blockIdx.x;
    const float *W, *b, *g, *bt, *m, *v;
    float *Wo, *Co;
    int K;
    if (job == 0) {
        W = fh_W1; b = fh_b1; g = fh_g1; bt = fh_bt1; m = fh_m1; v = fh_v1;
        Wo = ws + WT1_OFF; Co = ws + C1_OFF; K = 128;
    } else if (job == 1) {
        W = fh_W2; b = fh_b2; g = fh_g2; bt = fh_bt2; m = fh_m2; v = fh_v2;
        Wo = ws + WT2_OFF; Co = ws + C2_OFF; K = 64;
    } else if (job <= 4) {
        int l = job - 2;
        W = cW1 + l * 4096; b = cb1 + l * 64; g = cg1 + l * 64; bt = cbt1 + l * 64;
        m = cm1 + l * 64; v = cv1 + l * 64;
        Wo = ws + WTC1_OFF + l * 4096; Co = ws + CC1_OFF + l * 64; K = 64;
    } else {
        int l = job - 5;
        W = cW2 + l * 4096; b = cb2 + l * 64; g = cg2 + l * 64; bt = cbt2 + l * 64;
        m = cm2 + l * 64; v = cv2 + l * 64;
        Wo = ws + WTC2_OFF + l * 4096; Co = ws + CC2_OFF + l * 64; K = 64;
    }
    int tot = 64 * K;
    for (int i = threadIdx.x; i < tot; i += blockDim.x) {
        int j = i & 63;
        float s = g[j] * rsqrtf(v[j] + BN_EPS);
        Wo[i] = W[i] * s;   // [k][j] layout, scale column j
    }
    if (threadIdx.x < 64) {
        int j = threadIdx.x;
        float s = g[j] * rsqrtf(v[j] + BN_EPS);
        Co[j] = (b[j] - m[j]) * s + bt[j];
    }
}

// ---------------- CSR build ----------------
__global__ __launch_bounds__(256) void hist_kernel(const int* __restrict__ edges, int* __restrict__ cnt)
{
    int e = blockIdx.x * blockDim.x + threadIdx.x;
    if (e >= EE) return;
    atomicAdd(&cnt[edges[EE + e]], 1);
}

__global__ __launch_bounds__(SCAN_BLK) void scan_pass1(const int* __restrict__ cnt, int* __restrict__ bsum)
{
    __shared__ int r[SCAN_BLK];
    int t = threadIdx.x;
    int i = blockIdx.x * SCAN_BLK + t;
    r[t] = (i < NN) ? cnt[i] : 0;
    __syncthreads();
    for (int off = SCAN_BLK / 2; off > 0; off >>= 1) {
        if (t < off) r[t] += r[t + off];
        __syncthreads();
    }
    if (t == 0) bsum[blockIdx.x] = r[0];
}

__global__ __launch_bounds__(128) void scan_pass2(int* __restrict__ bsum)
{
    __shared__ int s[128];
    int t = threadIdx.x;
    int v = (t < SCAN_NBLK) ? bsum[t] : 0;
    s[t] = v;
    __syncthreads();
    for (int off = 1; off < 128; off <<= 1) {
        int a = (t >= off) ? s[t - off] : 0;
        __syncthreads();
        s[t] += a;
        __syncthreads();
    }
    if (t < SCAN_NBLK) bsum[t] = s[t] - v;   // exclusive
}

__global__ __launch_bounds__(SCAN_BLK) void scan_pass3(int* __restrict__ cnt, const int* __restrict__ bsum)
{
    __shared__ int s[SCAN_BLK];
    int t = threadIdx.x;
    int i = blockIdx.x * SCAN_BLK + t;
    int v = (i < NN) ? cnt[i] : 0;
    s[t] = v;
    __syncthreads();
    for (int off = 1; off < SCAN_BLK; off <<= 1) {
        int a = (t >= off) ? s[t - off] : 0;
        __syncthreads();
        s[t] += a;
        __syncthreads();
    }
    if (i < NN) cnt[i] = bsum[blockIdx.x] + s[t] - v;   // exclusive start
}

__global__ __launch_bounds__(256) void fill_kernel(
    const int* __restrict__ edges, int* __restrict__ cursor, int* __restrict__ col)
{
    int e = blockIdx.x * blockDim.x + threadIdx.x;
    if (e >= EE) return;
    int dst = edges[EE + e];
    int p = atomicAdd(&cursor[dst], 1);
    col[p] = edges[e];
}
// after fill: cursor[n] == row end; start = (n==0)?0:cursor[n-1]

// ---------------- gather: agg = x + sum x[src] from bf16 x; writes tiled f32 T ----------------
__global__ __launch_bounds__(256) void gather_t_kernel(
    const unsigned* __restrict__ xb, const int* __restrict__ cursor, const int* __restrict__ col,
    float* __restrict__ T)
{
    __shared__ float lds[64 * 65];
    int half = blockIdx.x & 1;
    int tile = blockIdx.x >> 1;
    int nbase = blockIdx.x << 6;
    int wv = threadIdx.x >> 6, lane = threadIdx.x & 63;
    int q = lane >> 3, c = lane & 7;   // 8 neighbor slots x 8 uint4-columns
    const uint4* x4 = (const uint4*)xb;
    for (int s = 0; s < 16; s++) {
        int i = wv * 16 + s;            // 0..63 within block
        int n = nbase + i;
        if (n < NN) {
            int st = (n == 0) ? 0 : cursor[n - 1];
            int en = cursor[n];
            float acc[8];
            if (q == 0) {
                uint4 u = x4[(long)n * 8 + c];
                acc[0] = bf_lo(u.x); acc[1] = bf_hi(u.x);
                acc[2] = bf_lo(u.y); acc[3] = bf_hi(u.y);
                acc[4] = bf_lo(u.z); acc[5] = bf_hi(u.z);
                acc[6] = bf_lo(u.w); acc[7] = bf_hi(u.w);
            } else {
#pragma unroll
                for (int r = 0; r < 8; r++) acc[r] = 0.f;
            }
            for (int b = st + q; b < en; b += 8) {
                int sc = col[b];
                uint4 u = x4[(long)sc * 8 + c];
                acc[0] += bf_lo(u.x); acc[1] += bf_hi(u.x);
                acc[2] += bf_lo(u.y); acc[3] += bf_hi(u.y);
                acc[4] += bf_lo(u.z); acc[5] += bf_hi(u.z);
                acc[6] += bf_lo(u.w); acc[7] += bf_hi(u.w);
            }
#pragma unroll
            for (int d = 8; d <= 32; d <<= 1) {
#pragma unroll
                for (int r = 0; r < 8; r++) acc[r] += __shfl_xor(acc[r], d);
            }
            if (q == 0) {
                int f = c << 3;
#pragma unroll
                for (int r = 0; r < 8; r++) lds[(f + r) * 65 + i] = acc[r];
            }
        }
    }
    __syncthreads();
    long gb = (long)tile * 8192 + (half << 6);
    for (int idx = threadIdx.x; idx < 4096; idx += 256) {
        int j = idx >> 6, i2 = idx & 63;
        T[gb + j * 128 + i2] = lds[j * 65 + i2];
    }
}

// ---------------- fused conv MLP: T (f32 tiled) -> x (bf16) ----------------
// block = 256 = 4 waves; lane = node (64/block), wave = output segment of 16.
// Weights stay wave-uniform -> scalar s_load; inputs via conflict-free LDS.
__global__ __launch_bounds__(256) void conv_fused_kernel(
    const float* __restrict__ T,
    const float* __restrict__ W1s, const float* __restrict__ C1v,
    const float* __restrict__ W2s, const float* __restrict__ C2v,
    unsigned* __restrict__ xb)
{
    __shared__ float ldsX[64 * 65];
    __shared__ float ldsH[64 * 65];
    int t = threadIdx.x;
    int il = t & 63;
    int wvu = __builtin_amdgcn_readfirstlane(t >> 6);   // force wave-uniform segment id
    int half = blockIdx.x & 1, tile = blockIdx.x >> 1;
    long gb = (long)tile * 8192 + (half << 6);
    // stage half-tile: feature k (0..63) x node i (0..63), coalesced
    for (int idx = t; idx < 4096; idx += 256) {
        int k = idx >> 6, i = idx & 63;
        ldsX[k * 65 + i] = T[gb + k * 128 + i];
    }
    __syncthreads();
    // layer 1: outputs [wvu*16, wvu*16+16)
    float a[16];
#pragma unroll
    for (int j = 0; j < 16; j++) a[j] = C1v[wvu * 16 + j];
#pragma unroll 4
    for (int k = 0; k < 64; k++) {
        float xk = ldsX[k * 65 + il];
        const float* w = W1s + k * 64 + wvu * 16;
#pragma unroll
        for (int j = 0; j < 16; j++) a[j] += xk * w[j];
    }
#pragma unroll
    for (int j = 0; j < 16; j++) ldsH[(wvu * 16 + j) * 65 + il] = fmaxf(a[j], 0.f);
    __syncthreads();
    // layer 2
    float o[16];
#pragma unroll
    for (int j = 0; j < 16; j++) o[j] = C2v[wvu * 16 + j];
#pragma unroll 4
    for (int k = 0; k < 64; k++) {
        float hk = ldsH[k * 65 + il];
        const float* w = W2s + k * 64 + wvu * 16;
#pragma unroll
        for (int j = 0; j < 16; j++) o[j] += hk * w[j];
    }
    int n = (blockIdx.x << 6) + il;
    if (n < NN) {
        unsigned u[8];
#pragma unroll
        for (int p = 0; p < 8; p++) {
            float lo = fmaxf(o[2 * p], 0.f), hi = fmaxf(o[2 * p + 1], 0.f);
            u[p] = f2bf(lo) | (f2bf(hi) << 16);
        }
        uint4* xo = (uint4*)(xb + ((long)n << 5) + (wvu << 3));
        xo[0] = make_uint4(u[0], u[1], u[2], u[3]);
        xo[1] = make_uint4(u[4], u[5], u[6], u[7]);
    }
}

// ---------------- fused first MLP: embedding -> x (bf16), same wave-seg scheme ----------------
__global__ __launch_bounds__(256) void embed_fused_kernel(
    const int* __restrict__ node_ids, const float* __restrict__ emb,
    const float* __restrict__ W1s, const float* __restrict__ C1v,
    const float* __restrict__ W2s, const float* __restrict__ C2v,
    unsigned* __restrict__ xb)
{
    __shared__ float ldsE[64 * 129];
    __shared__ float ldsH[64 * 65];
    __shared__ int sh_nid[64];
    int t = threadIdx.x;
    int il = t & 63;
    int wvu = __builtin_amdgcn_readfirstlane(t >> 6);
    int nbase = blockIdx.x << 6;
    if (t < 64) {
        int n = nbase + t;
        sh_nid[t] = (n < NN) ? node_ids[n] : 0;
    }
    __syncthreads();
    // stage 64 embedding rows (128 floats each), coalesced 256B bursts
    for (int idx = t; idx < 8192; idx += 256) {
        int r = idx >> 7, c = idx & 127;
        ldsE[r * 129 + c] = emb[(long)sh_nid[r] * 128 + c];
    }
    __syncthreads();
    // layer 1
    float a[16];
#pragma unroll
    for (int j = 0; j < 16; j++) a[j] = C1v[wvu * 16 + j];
#pragma unroll 4
    for (int k = 0; k < 128; k++) {
        float ek = ldsE[il * 129 + k];
        const float* w = W1s + k * 64 + wvu * 16;
#pragma unroll
        for (int j = 0; j < 16; j++) a[j] += ek * w[j];
    }
#pragma unroll
    for (int j = 0; j < 16; j++) ldsH[(wvu * 16 + j) * 65 + il] = fmaxf(a[j], 0.f);
    __syncthreads();
    // layer 2
    float o[16];
#pragma unroll
    for (int j = 0; j < 16; j++) o[j] = C2v[wvu * 16 + j];
#pragma unroll 4
    for (int k = 0; k < 64; k++) {
        float hk = ldsH[k * 65 + il];
        const float* w = W2s + k * 64 + wvu * 16;
#pragma unroll
        for (int j = 0; j < 16; j++) o[j] += hk * w[j];
    }
    int n = nbase + il;
    if (n < NN) {
        unsigned u[8];
#pragma unroll
        for (int p = 0; p < 8; p++) {
            float lo = fmaxf(o[2 * p], 0.f), hi = fmaxf(o[2 * p + 1], 0.f);
            u[p] = f2bf(lo) | (f2bf(hi) << 16);
        }
        uint4* xo = (uint4*)(xb + ((long)n << 5) + (wvu << 3));
        xo[0] = make_uint4(u[0], u[1], u[2], u[3]);
        xo[1] = make_uint4(u[4], u[5], u[6], u[7]);
    }
}

// ---------------- graph pooling over sorted batch from bf16 x ----------------
#define POOL_WAVES 4096
#define POOL_CHUNK ((NN + POOL_WAVES - 1) / POOL_WAVES)   // 25
__global__ __launch_bounds__(256) void pool_kernel(
    const unsigned short* __restrict__ xb, const int* __restrict__ batch,
    float* __restrict__ pooled, float* __restrict__ cnt)
{
    int wave = (blockIdx.x * blockDim.x + threadIdx.x) >> 6;
    int lane = threadIdx.x & 63;
    int start = wave * POOL_CHUNK;
    int end = start + POOL_CHUNK;
    if (end > NN) end = NN;
    if (start >= end) return;
    int g_cur = batch[start];
    float acc = 0.f, c = 0.f;
    for (int n = start; n < end; ++n) {
        int g = batch[n];
        if (g != g_cur) {
            unsafeAtomicAdd(&pooled[(long)g_cur * 64 + lane], acc);
            if (cnt != nullptr && lane == 0) unsafeAtomicAdd(&cnt[g_cur], c);
            acc = 0.f; c = 0.f; g_cur = g;
        }
        acc += __uint_as_float(((unsigned)xb[(long)n * 64 + lane]) << 16);
        c += 1.f;
    }
    unsafeAtomicAdd(&pooled[(long)g_cur * 64 + lane], acc);
    if (cnt != nullptr && lane == 0) unsafeAtomicAdd(&cnt[g_cur], c);
}

// ---------------- readout + softmax ----------------
__global__ void final_kernel(
    const float* __restrict__ pooled, const float* __restrict__ cnt,
    const float* __restrict__ linW, const float* __restrict__ linb,
    float* __restrict__ outp)
{
    int g = threadIdx.x;
    if (g >= GG) return;
    float z0 = 0.f, z1 = 0.f;
    float c = cnt[g];
    for (int l = 0; l < 4; l++) {
        const float* p = pooled + (long)l * GG * 64 + (long)g * 64;
        const float* W = linW + l * 128;
        float bscale = (l == 0) ? c : 1.f;   // layer0 bias summed per node; others once
        float s0 = linb[l * 2 + 0] * bscale;
        float s1 = linb[l * 2 + 1] * bscale;
        for (int k = 0; k < 64; k++) {
            float pk = p[k];
            s0 += pk * W[k * 2 + 0];
            s1 += pk * W[k * 2 + 1];
        }
        z0 += s0; z1 += s1;
    }
    float mx = fmaxf(z0, z1);
    float e0 = expf(z0 - mx), e1 = expf(z1 - mx);
    float inv = 1.f / (e0 + e1);
    outp[g * 2 + 0] = e0 * inv;
    outp[g * 2 + 1] = e1 * inv;
}

extern "C" void kernel_launch(void* const* d_in, const int* in_sizes, int n_in,
                              void* d_out, int out_size, void* d_ws, size_t ws_size,
                              hipStream_t stream) {
    const int*   node_ids = (const int*)d_in[0];
    const int*   edges    = (const int*)d_in[1];
    const int*   batch    = (const int*)d_in[2];
    const float* emb      = (const float*)d_in[3];
    const float* fh_W1 = (const float*)d_in[4];
    const float* fh_b1 = (const float*)d_in[5];
    const float* fh_g1 = (const float*)d_in[6];
    const float* fh_bt1 = (const float*)d_in[7];
    const float* fh_m1 = (const float*)d_in[8];
    const float* fh_v1 = (const float*)d_in[9];
    const float* fh_W2 = (const float*)d_in[10];
    const float* fh_b2 = (const float*)d_in[11];
    const float* fh_g2 = (const float*)d_in[12];
    const float* fh_bt2 = (const float*)d_in[13];
    const float* fh_m2 = (const float*)d_in[14];
    const float* fh_v2 = (const float*)d_in[15];
    const float* cW1 = (const float*)d_in[16];
    const float* cb1 = (const float*)d_in[17];
    const float* cg1 = (const float*)d_in[18];
    const float* cbt1 = (const float*)d_in[19];
    const float* cm1 = (const float*)d_in[20];
    const float* cv1 = (const float*)d_in[21];
    const float* cW2 = (const float*)d_in[22];
    const float* cb2 = (const float*)d_in[23];
    const float* cg2 = (const float*)d_in[24];
    const float* cbt2 = (const float*)d_in[25];
    const float* cm2 = (const float*)d_in[26];
    const float* cv2 = (const float*)d_in[27];
    const float* linW = (const float*)d_in[28];
    const float* linb = (const float*)d_in[29];

    float*    ws     = (float*)d_ws;
    int*      cursor = (int*)(ws + CUR_OFF);
    int*      col    = (int*)(ws + COL_OFF);
    int*      bsum   = (int*)(ws + BSUM_OFF);
    float*    Tt     = ws + T_OFF;
    unsigned* xb     = (unsigned*)(ws + X_OFF);

    prep_kernel<<<8, 256, 0, stream>>>(
        fh_W1, fh_b1, fh_g1, fh_bt1, fh_m1, fh_v1,
        fh_W2, fh_b2, fh_g2, fh_bt2, fh_m2, fh_v2,
        cW1, cb1, cg1, cbt1, cm1, cv1,
        cW2, cb2, cg2, cbt2, cm2, cv2, ws);

    hipMemsetAsync(ws + POOL_OFF, 0, (4L * GG * 64 + GG) * sizeof(float), stream);
    hipMemsetAsync(cursor, 0, NN * sizeof(int), stream);

    // CSR build (dst-indexed, single-pass fill)
    hist_kernel<<<(EE + 255) / 256, 256, 0, stream>>>(edges, cursor);
    scan_pass1<<<SCAN_NBLK, SCAN_BLK, 0, stream>>>(cursor, bsum);
    scan_pass2<<<1, 128, 0, stream>>>(bsum);
    scan_pass3<<<SCAN_NBLK, SCAN_BLK, 0, stream>>>(cursor, bsum);
    fill_kernel<<<(EE + 255) / 256, 256, 0, stream>>>(edges, cursor, col);

    const int FBLK = NT * 2;   // 1564 blocks (64 nodes each)

    embed_fused_kernel<<<FBLK, 256, 0, stream>>>(
        node_ids, emb, ws + WT1_OFF, ws + C1_OFF, ws + WT2_OFF, ws + C2_OFF, xb);

    pool_kernel<<<POOL_WAVES / 4, 256, 0, stream>>>(
        (const unsigned short*)xb, batch, ws + POOL_OFF, ws + CNT_OFF);

    for (int l = 0; l < 3; l++) {
        gather_t_kernel<<<FBLK, 256, 0, stream>>>(xb, cursor, col, Tt);
        conv_fused_kernel<<<FBLK, 256, 0, stream>>>(
            Tt, ws + WTC1_OFF + l * 4096, ws + CC1_OFF + l * 64,
            ws + WTC2_OFF + l * 4096, ws + CC2_OFF + l * 64, xb);
        pool_kernel<<<POOL_WAVES / 4, 256, 0, stream>>>(
            (const unsigned short*)xb, batch, ws + POOL_OFF + (long)(l + 1) * GG * 64, nullptr);
    }

    final_kernel<<<1, 128, 0, stream>>>(
        ws + POOL_OFF, ws + CNT_OFF, linW, linb, (float*)d_out);
}